// Round 2
// baseline (59420.184 us; speedup 1.0000x reference)
//
#include <hip/hip_runtime.h>
#include <hip/hip_bf16.h>
#include <math.h>

// ---------------------------------------------------------------------------
// VRNN on MI355X — Round 2: correctness-first fp32, CHUNKED to fit ws_size.
// Round 0/1 crashed with a memory fault: the workspace map assumed ~619 MB
// without checking ws_size. This round plans buffers for a chunk of TC
// timesteps and picks the largest TC (divisor of 256) that fits ws_size.
// Per chunk: phi_x GEMM -> sequential t-loop (enc/heads/GRU, histories in
// bf16) -> batched prior+KLD and dec+NLL/rec for the chunk.
// ---------------------------------------------------------------------------

#define TM 32
#define TN 64
#define KT 16

// C[M,N] = act( bias + sum_segs A_s @ W_s^T ), W row-major (N, ldw), A row-major (M, lda)
__global__ __launch_bounds__(256) void gemm_k(
    int M, int N,
    const void* __restrict__ A0, int lda0, const float* __restrict__ W0, int ldw0, int K0, int abf0,
    const void* __restrict__ A1, int lda1, const float* __restrict__ W1, int ldw1, int K1, int abf1,
    const float* __restrict__ bias, int act,
    float* __restrict__ C, int ldc)
{
    __shared__ float As[KT][36];   // [k][m], +4 pad
    __shared__ float Ws[KT][68];   // [k][n], +4 pad
    const int tid = threadIdx.x;
    const int tx = tid & 15;
    const int ty = tid >> 4;
    const int n0 = blockIdx.x * TN;
    const int m0 = blockIdx.y * TM;

    float acc[2][4];
#pragma unroll
    for (int i = 0; i < 2; ++i)
#pragma unroll
        for (int j = 0; j < 4; ++j) acc[i][j] = 0.f;

    const int ar = tid >> 3;        // 0..31 (A row in tile)
    const int ak = (tid & 7) * 2;   // 0..14 (A k in tile, float2)
    const int wr = tid >> 2;        // 0..63 (W row in tile)
    const int wk = (tid & 3) * 4;   // 0..12 (W k in tile, float4)

    for (int s = 0; s < 2; ++s) {
        const void* Av = s ? A1 : A0;
        if (Av == nullptr) continue;
        const float* W = s ? W1 : W0;
        const int lda = s ? lda1 : lda0;
        const int ldw = s ? ldw1 : ldw0;
        const int K   = s ? K1 : K0;
        const int abf = s ? abf1 : abf0;
        for (int k0 = 0; k0 < K; k0 += KT) {
            float a0v, a1v;
            if (abf) {
                const __hip_bfloat16* Ab = (const __hip_bfloat16*)Av + (size_t)(m0 + ar) * lda + (k0 + ak);
                a0v = __bfloat162float(Ab[0]);
                a1v = __bfloat162float(Ab[1]);
            } else {
                const float* Af = (const float*)Av + (size_t)(m0 + ar) * lda + (k0 + ak);
                a0v = Af[0]; a1v = Af[1];
            }
            float4 wv = make_float4(0.f, 0.f, 0.f, 0.f);
            const int n = n0 + wr;
            if (n < N) wv = *(const float4*)(W + (size_t)n * ldw + (k0 + wk));

            __syncthreads();   // protect LDS from previous tile's readers
            As[ak][ar]     = a0v;
            As[ak + 1][ar] = a1v;
            Ws[wk][wr]     = wv.x;
            Ws[wk + 1][wr] = wv.y;
            Ws[wk + 2][wr] = wv.z;
            Ws[wk + 3][wr] = wv.w;
            __syncthreads();

#pragma unroll
            for (int kk = 0; kk < KT; ++kk) {
                float2 av = *(const float2*)&As[kk][ty * 2];
                float4 bv = *(const float4*)&Ws[kk][tx * 4];
                acc[0][0] += av.x * bv.x; acc[0][1] += av.x * bv.y;
                acc[0][2] += av.x * bv.z; acc[0][3] += av.x * bv.w;
                acc[1][0] += av.y * bv.x; acc[1][1] += av.y * bv.y;
                acc[1][2] += av.y * bv.z; acc[1][3] += av.y * bv.w;
            }
        }
    }

#pragma unroll
    for (int i = 0; i < 2; ++i) {
        const int m = m0 + ty * 2 + i;
#pragma unroll
        for (int j = 0; j < 4; ++j) {
            const int n = n0 + tx * 4 + j;
            if (n < N) {
                float v = acc[i][j];
                if (bias) v += bias[n];
                if (act)  v = fmaxf(v, 0.f);
                C[(size_t)m * ldc + n] = v;
            }
        }
    }
}

__device__ __forceinline__ float softplus_f(float v) {
    return (v > 20.f) ? v : log1pf(expf(v));
}

// heads: enc_mean/enc_std from enc_h, then z = eps*std+mean (cols 0..3 *10),
// then phi_z = relu(z @ pzW^T + pzb). 64 blocks x 8 rows.
__global__ __launch_bounds__(256) void heads_kernel(
    const float* __restrict__ ench,                     // [512,512]
    const float* __restrict__ mW, const float* __restrict__ mB,   // (32,512),(32)
    const float* __restrict__ sW, const float* __restrict__ sB,
    const float* __restrict__ eps_t,                    // [512,32]
    const float* __restrict__ pzW, const float* __restrict__ pzB, // (512,32),(512)
    float* __restrict__ meanh, float* __restrict__ stdh,          // [512,32]
    float* __restrict__ phizt, __hip_bfloat16* __restrict__ phizh) // [512,512]
{
    __shared__ float Es[8][512];
    __shared__ float Ms[8][32];
    __shared__ float Ss[8][32];
    __shared__ float Zs[8][32];
    const int tid = threadIdx.x;
    const int m0 = blockIdx.x * 8;

    for (int i = tid; i < 8 * 512; i += 256)
        Es[i >> 9][i & 511] = ench[(size_t)(m0 + (i >> 9)) * 512 + (i & 511)];
    __syncthreads();

    const int o = tid & 63;          // 0..31 mean, 32..63 std
    const int c = o & 31;
    const float* Wr = (o < 32 ? mW : sW) + (size_t)c * 512;
    const float bse = (o < 32 ? mB[c] : sB[c]);
    const int r0 = tid >> 6;         // 0..3
    const int r1 = r0 + 4;
    float a0 = bse, a1 = bse;
#pragma unroll 4
    for (int k = 0; k < 512; ++k) {
        float w = Wr[k];
        a0 += Es[r0][k] * w;
        a1 += Es[r1][k] * w;
    }
    if (o < 32) {
        Ms[r0][c] = a0; Ms[r1][c] = a1;
        meanh[(m0 + r0) * 32 + c] = a0;
        meanh[(m0 + r1) * 32 + c] = a1;
    } else {
        float s0 = softplus_f(a0);
        float s1 = softplus_f(a1);
        Ss[r0][c] = s0; Ss[r1][c] = s1;
        stdh[(m0 + r0) * 32 + c] = s0;
        stdh[(m0 + r1) * 32 + c] = s1;
    }
    __syncthreads();

    {   // z: 8 rows x 32 cols = 256 threads
        const int r = tid >> 5, cc = tid & 31;
        float zv = eps_t[(size_t)(m0 + r) * 32 + cc] * Ss[r][cc] + Ms[r][cc];
        if (cc < 4) zv *= 10.f;
        Zs[r][cc] = zv;
    }
    __syncthreads();

    for (int idx = tid; idx < 8 * 512; idx += 256) {
        const int r = idx >> 9, cc = idx & 511;
        float acc = pzB[cc];
        const float* w = pzW + (size_t)cc * 32;
#pragma unroll
        for (int k = 0; k < 32; ++k) acc += Zs[r][k] * w[k];
        acc = fmaxf(acc, 0.f);
        const size_t g = (size_t)(m0 + r) * 512 + cc;
        phizt[g] = acc;
        phizh[g] = __float2bfloat16(acc);
    }
}

// GRU gates: h_new = (1-z)*n + z*h,  n = tanh(xn + r*hn)
__global__ __launch_bounds__(256) void gates_kernel(
    const float* __restrict__ Gx, const float* __restrict__ Gh,
    float* __restrict__ h, __hip_bfloat16* __restrict__ hnext)
{
    const int idx = blockIdx.x * 256 + threadIdx.x;   // 262144
    const int m = idx >> 9, j = idx & 511;
    const size_t b = (size_t)m * 1536 + j;
    const float xr = Gx[b], xz = Gx[b + 512], xn = Gx[b + 1024];
    const float hr = Gh[b], hz = Gh[b + 512], hn = Gh[b + 1024];
    const float hv = h[idx];
    const float r  = 1.f / (1.f + expf(-(xr + hr)));
    const float zg = 1.f / (1.f + expf(-(xz + hz)));
    const float n  = tanhf(xn + r * hn);
    const float hnew = (1.f - zg) * n + zg * hv;
    h[idx] = hnew;
    hnext[idx] = __float2bfloat16(hnew);
}

__global__ __launch_bounds__(256) void init_kernel(
    float* __restrict__ h, __hip_bfloat16* __restrict__ hch0, float* __restrict__ out)
{
    const int idx = blockIdx.x * 256 + threadIdx.x;
    if (idx < 262144) { h[idx] = 0.f; hch0[idx] = __float2bfloat16(0.f); }
    if (idx < 3) out[idx] = 0.f;
}

// copy bf16 h-slot (chunk handoff): dst = src, 262144 elems
__global__ __launch_bounds__(256) void snap_kernel(
    const __hip_bfloat16* __restrict__ src, __hip_bfloat16* __restrict__ dst)
{
    const int idx = blockIdx.x * 256 + threadIdx.x;
    dst[idx] = src[idx];
}

// KLD over NROWS*32 elements -> atomicAdd(out+1). grid = NROWS*32/1024
__global__ __launch_bounds__(256) void kld_kernel(
    const float* __restrict__ emean, const float* __restrict__ estd,
    const float* __restrict__ pmean, const float* __restrict__ psraw,
    float* __restrict__ out)
{
    const size_t i0 = (size_t)blockIdx.x * 1024 + threadIdx.x;
    float acc = 0.f;
#pragma unroll
    for (int rep = 0; rep < 4; ++rep) {
        const size_t i = i0 + (size_t)rep * 256;
        const float s1 = fmaxf(estd[i], 1e-9f);
        const float m1 = emean[i];
        const float s2 = fmaxf(softplus_f(psraw[i]), 1e-9f);
        const float m2 = pmean[i];
        const float dm = m1 - m2;
        acc += 2.f * (logf(s2) - logf(s1)) + (s1 * s1 + dm * dm) / (s2 * s2) - 1.f;
    }
    for (int off = 32; off > 0; off >>= 1) acc += __shfl_down(acc, off);
    __shared__ float tmp[4];
    if ((threadIdx.x & 63) == 0) tmp[threadIdx.x >> 6] = acc;
    __syncthreads();
    if (threadIdx.x == 0)
        atomicAdd(out + 1, 0.5f * (tmp[0] + tmp[1] + tmp[2] + tmp[3]));
}

// dec_mean2 (K=64,N=64) + dec_means write + rec/nll reductions. 32 rows/block.
__global__ __launch_bounds__(256) void final_kernel(
    const float* __restrict__ dmh,      // [rows,64]
    const float* __restrict__ W2,       // (64,64)
    const float* __restrict__ b2,       // (64)
    const float* __restrict__ dstdraw,  // [rows,64]
    const float* __restrict__ x,        // [rows,64]
    float* __restrict__ sums,           // [0]=rec, [2]=nll
    float* __restrict__ outDM)          // dec_means for this chunk
{
    __shared__ float Dh[32][64];
    __shared__ float W2s[64][65];
    const int tid = threadIdx.x;
    const size_t r0 = (size_t)blockIdx.x * 32;

    for (int i = tid; i < 32 * 64; i += 256) Dh[i >> 6][i & 63] = dmh[r0 * 64 + i];
    for (int i = tid; i < 64 * 64; i += 256) W2s[i >> 6][i & 63] = W2[i];
    __syncthreads();

    float rec = 0.f, nll = 0.f;
#pragma unroll
    for (int rep = 0; rep < 8; ++rep) {
        const int idx = rep * 256 + tid;
        const int r = idx >> 6, j = idx & 63;
        float acc = b2[j];
#pragma unroll 8
        for (int k = 0; k < 64; ++k) acc += Dh[r][k] * W2s[j][k];
        const size_t g = (r0 + r) * 64 + j;
        const float xv = x[g];
        const float sd = softplus_f(dstdraw[g]);
        outDM[g] = acc;
        const float d = xv - acc;
        rec += d * d;
        nll += logf(sd + 1e-5f) + 0.9189385332046727f + d * d / (2.f * sd * sd);
    }
    for (int off = 32; off > 0; off >>= 1) {
        rec += __shfl_down(rec, off);
        nll += __shfl_down(nll, off);
    }
    __shared__ float rr[4], nn[4];
    if ((tid & 63) == 0) { rr[tid >> 6] = rec; nn[tid >> 6] = nll; }
    __syncthreads();
    if (tid == 0) {
        atomicAdd(sums + 0, rr[0] + rr[1] + rr[2] + rr[3]);
        atomicAdd(sums + 2, nn[0] + nn[1] + nn[2] + nn[3]);
    }
}

// ---------------------------------------------------------------------------

static void gemm(hipStream_t s, int M, int N,
                 const void* A0, int lda0, const float* W0, int ldw0, int K0, int abf0,
                 const void* A1, int lda1, const float* W1, int ldw1, int K1, int abf1,
                 const float* bias, int act, float* C, int ldc)
{
    dim3 g((N + TN - 1) / TN, M / TM), b(256);
    hipLaunchKernelGGL(gemm_k, g, b, 0, s,
                       M, N, A0, lda0, W0, ldw0, K0, abf0,
                       A1, lda1, W1, ldw1, K1, abf1, bias, act, C, ldc);
}

// workspace bytes needed for chunk length tc
static size_t ws_needed(int tc) {
    size_t per = 3ull * 1048576ull            // PHIX, RA, RB (fp32 [tc*512,512])
               + 2ull * 524288ull             // PHIZC, HCH (bf16 [tc*512,512])
               + 4ull * 65536ull              // EMC, ESC, PM, PS ([tc*512,32] f32)
               + 2ull * 131072ull;            // DMH, DSTD ([tc*512,64] f32)
    size_t fixed = 524288ull                  // HCH extra slot (bf16 [512,512])
                 + 4ull * 1048576ull          // EH1, ENCH, PHIZT, HLIVE
                 + 2ull * 3145728ull;         // GXB, GHB
    return per * (size_t)tc + fixed;
}

extern "C" void kernel_launch(void* const* d_in, const int* in_sizes, int n_in,
                              void* d_out, int out_size, void* d_ws, size_t ws_size,
                              hipStream_t stream)
{
    const float* x_in   = (const float*)d_in[0];
    const float* eps_in = (const float*)d_in[1];
    const float* pxW1 = (const float*)d_in[2];  const float* pxb1 = (const float*)d_in[3];
    const float* pxW2 = (const float*)d_in[4];  const float* pxb2 = (const float*)d_in[5];
    const float* pzW  = (const float*)d_in[6];  const float* pzb  = (const float*)d_in[7];
    const float* eW1  = (const float*)d_in[8];  const float* eb1  = (const float*)d_in[9];
    const float* eW2  = (const float*)d_in[10]; const float* eb2  = (const float*)d_in[11];
    const float* emW  = (const float*)d_in[12]; const float* emb  = (const float*)d_in[13];
    const float* esW  = (const float*)d_in[14]; const float* esb  = (const float*)d_in[15];
    const float* prW  = (const float*)d_in[16]; const float* prb  = (const float*)d_in[17];
    const float* pmW  = (const float*)d_in[18]; const float* pmb  = (const float*)d_in[19];
    const float* psW  = (const float*)d_in[20]; const float* psb  = (const float*)d_in[21];
    const float* dW1  = (const float*)d_in[22]; const float* db1  = (const float*)d_in[23];
    const float* dW2  = (const float*)d_in[24]; const float* db2  = (const float*)d_in[25];
    const float* dsW  = (const float*)d_in[26]; const float* dsb  = (const float*)d_in[27];
    const float* dmW1 = (const float*)d_in[28]; const float* dmb1 = (const float*)d_in[29];
    const float* dmW2 = (const float*)d_in[30]; const float* dmb2 = (const float*)d_in[31];
    const float* gWih = (const float*)d_in[32]; const float* gWhh = (const float*)d_in[33];

    float* out = (float*)d_out;
    char* ws = (char*)d_ws;

    // pick largest chunk length (divisor of 256) that fits ws_size
    int TC = 1;
    const int cands[9] = {256, 128, 64, 32, 16, 8, 4, 2, 1};
    for (int i = 0; i < 9; ++i) {
        if (ws_needed(cands[i]) <= ws_size) { TC = cands[i]; break; }
    }
    const int NCH = 256 / TC;
    const size_t S4 = (size_t)TC * 1048576ull;   // fp32 [TC*512,512] bytes
    const size_t S2 = (size_t)TC * 524288ull;    // bf16 [TC*512,512] bytes

    size_t off = 0;
    float* PHIX = (float*)(ws + off); off += S4;
    float* RA   = (float*)(ws + off); off += S4;   // px1 / prior_h / dec_eh
    float* RB   = (float*)(ws + off); off += S4;   // dec_h
    __hip_bfloat16* PHIZC = (__hip_bfloat16*)(ws + off); off += S2;
    __hip_bfloat16* HCH   = (__hip_bfloat16*)(ws + off); off += S2 + 524288ull; // TC+1 slots
    float* EMC  = (float*)(ws + off); off += (size_t)TC * 65536ull;
    float* ESC  = (float*)(ws + off); off += (size_t)TC * 65536ull;
    float* PM   = (float*)(ws + off); off += (size_t)TC * 65536ull;
    float* PS   = (float*)(ws + off); off += (size_t)TC * 65536ull;
    float* DMH  = (float*)(ws + off); off += (size_t)TC * 131072ull;
    float* DSTD = (float*)(ws + off); off += (size_t)TC * 131072ull;
    float* EH1  = (float*)(ws + off); off += 1048576ull;
    float* ENCH = (float*)(ws + off); off += 1048576ull;
    float* PHIZT= (float*)(ws + off); off += 1048576ull;
    float* HLIVE= (float*)(ws + off); off += 1048576ull;
    float* GXB  = (float*)(ws + off); off += 3145728ull;
    float* GHB  = (float*)(ws + off); off += 3145728ull;

    hipLaunchKernelGGL(init_kernel, dim3(1024), dim3(256), 0, stream, HLIVE, HCH, out);

    for (int c = 0; c < NCH; ++c) {
        const int cs = c * TC;               // chunk start timestep
        const int MR = TC * 512;             // chunk rows

        if (c > 0)  // h at chunk start = last slot of previous chunk
            hipLaunchKernelGGL(snap_kernel, dim3(1024), dim3(256), 0, stream,
                               HCH + (size_t)TC * 262144, HCH);

        // ---- phi_x for the chunk ----
        gemm(stream, MR, 512, x_in + (size_t)cs * 32768, 64, pxW1, 64, 64, 0,
             nullptr, 0, nullptr, 0, 0, 0, pxb1, 1, RA, 512);
        gemm(stream, MR, 512, RA, 512, pxW2, 512, 512, 0,
             nullptr, 0, nullptr, 0, 0, 0, pxb2, 1, PHIX, 512);

        // ---- sequential steps ----
        for (int lt = 0; lt < TC; ++lt) {
            const int t = cs + lt;
            const float* phix_t = PHIX + (size_t)lt * 262144;
            gemm(stream, 512, 512, phix_t, 512, eW1, 1024, 512, 0,
                 HLIVE, 512, eW1 + 512, 1024, 512, 0, eb1, 1, EH1, 512);
            gemm(stream, 512, 512, EH1, 512, eW2, 512, 512, 0,
                 nullptr, 0, nullptr, 0, 0, 0, eb2, 1, ENCH, 512);
            hipLaunchKernelGGL(heads_kernel, dim3(64), dim3(256), 0, stream,
                               ENCH, emW, emb, esW, esb,
                               eps_in + (size_t)t * 16384, pzW, pzb,
                               EMC + (size_t)lt * 16384, ESC + (size_t)lt * 16384,
                               PHIZT, PHIZC + (size_t)lt * 262144);
            gemm(stream, 512, 1536, phix_t, 512, gWih, 1024, 512, 0,
                 PHIZT, 512, gWih + 512, 1024, 512, 0, nullptr, 0, GXB, 1536);
            gemm(stream, 512, 1536, HLIVE, 512, gWhh, 512, 512, 0,
                 nullptr, 0, nullptr, 0, 0, 0, nullptr, 0, GHB, 1536);
            hipLaunchKernelGGL(gates_kernel, dim3(1024), dim3(256), 0, stream,
                               GXB, GHB, HLIVE, HCH + (size_t)(lt + 1) * 262144);
        }

        // ---- post: prior + KLD ----
        gemm(stream, MR, 512, HCH, 512, prW, 512, 512, 1,
             nullptr, 0, nullptr, 0, 0, 0, prb, 1, RA, 512);
        gemm(stream, MR, 32, RA, 512, pmW, 512, 512, 0,
             nullptr, 0, nullptr, 0, 0, 0, pmb, 0, PM, 32);
        gemm(stream, MR, 32, RA, 512, psW, 512, 512, 0,
             nullptr, 0, nullptr, 0, 0, 0, psb, 0, PS, 32);
        hipLaunchKernelGGL(kld_kernel, dim3(TC * 16), dim3(256), 0, stream,
                           EMC, ESC, PM, PS, out);

        // ---- post: dec + NLL/rec ----
        gemm(stream, MR, 512, PHIZC, 512, dW1, 1024, 512, 1,
             HCH, 512, dW1 + 512, 1024, 512, 1, db1, 1, RA, 512);
        gemm(stream, MR, 512, RA, 512, dW2, 512, 512, 0,
             nullptr, 0, nullptr, 0, 0, 0, db2, 1, RB, 512);
        gemm(stream, MR, 64, RB, 512, dmW1, 512, 512, 0,
             nullptr, 0, nullptr, 0, 0, 0, dmb1, 1, DMH, 64);
        gemm(stream, MR, 64, RB, 512, dsW, 512, 512, 0,
             nullptr, 0, nullptr, 0, 0, 0, dsb, 0, DSTD, 64);
        hipLaunchKernelGGL(final_kernel, dim3(MR / 32), dim3(256), 0, stream,
                           DMH, dmW2, dmb2, DSTD, x_in + (size_t)cs * 32768,
                           out, out + 3 + (size_t)cs * 32768);
    }
}

// Round 3
// 22562.819 us; speedup vs baseline: 2.6335x; 2.6335x over previous
//
#include <hip/hip_runtime.h>
#include <hip/hip_bf16.h>
#include <math.h>

// ---------------------------------------------------------------------------
// VRNN on MI355X — Round 3: bf16 MFMA everywhere.
// - One flexible MFMA GEMM (16x16x32 bf16, fp32 acc): C = act(bias + sum of
//   up to 2 segments A_s @ W_s^T). A,W bf16 K-contiguous; out fp32 or bf16.
// - Sequential step = 4 launches: enc1(G), enc2(G), encheads(fused ms GEMM +
//   softplus + z-sample + phi_z GEMM), gru(fused gx/gh GEMMs + gate math).
// - Heads packed: enc/prior mean||std -> N=64 GEMMs w/ fused softplus;
//   dec_mean1||dec_std -> N=128 GEMM.
// - Weights converted to bf16 once per call. Chunked ws plan (TC adaptive).
// ---------------------------------------------------------------------------

typedef __attribute__((ext_vector_type(8))) short bfrag;   // 8 x bf16
typedef __attribute__((ext_vector_type(4))) float ffrag;   // 4 x f32
typedef __hip_bfloat16 bf16;

__device__ __forceinline__ float softplus_f(float v) {
    return (v > 20.f) ? v : log1pf(expf(v));
}
__device__ __forceinline__ float sigmoid_f(float v) {
    return 1.f / (1.f + expf(-v));
}

// ---- setup converters ----
__global__ __launch_bounds__(256) void f2b_kernel(
    const float* __restrict__ s, bf16* __restrict__ d, int n)
{
    int i = blockIdx.x * 256 + threadIdx.x;
    if (i < n) d[i] = __float2bfloat16(s[i]);
}
__global__ __launch_bounds__(256) void fcopy_kernel(
    const float* __restrict__ s, float* __restrict__ d, int n)
{
    int i = blockIdx.x * 256 + threadIdx.x;
    if (i < n) d[i] = s[i];
}

__global__ __launch_bounds__(256) void init_kernel(
    float* __restrict__ hlive, bf16* __restrict__ hh0, float* __restrict__ out)
{
    const int idx = blockIdx.x * 256 + threadIdx.x;
    if (idx < 262144) { hlive[idx] = 0.f; hh0[idx] = __float2bfloat16(0.f); }
    if (idx < 3) out[idx] = 0.f;
}

__global__ __launch_bounds__(256) void snap_kernel(
    const bf16* __restrict__ src, bf16* __restrict__ dst)
{
    const int idx = blockIdx.x * 256 + threadIdx.x;
    dst[idx] = src[idx];
}

// ---------------------------------------------------------------------------
// MFMA GEMM: C[M,N] = act(bias + sum_s A_s @ W_s^T)
// A [M,lda] bf16 row-major, W [N,ldw] bf16 row-major (K-contig both).
// Requires: M%64==0, N%64==0, K%32==0. Grid (N/64, M/64), 256 thr (4 waves),
// wave tile 32x32 (2x2 MFMA subtiles). No LDS (L1/L2 handle reuse).
// act: 0 none, 1 relu, 2 softplus on col>=32, 3 relu on col<64 only.
// obf: 1 -> bf16 out, 0 -> fp32 out.
// ---------------------------------------------------------------------------
__global__ __launch_bounds__(256) void mfma_gemm(
    const bf16* __restrict__ A0, int lda0, const bf16* __restrict__ W0, int ldw0, int K0,
    const bf16* __restrict__ A1, int lda1, const bf16* __restrict__ W1, int ldw1, int K1,
    const float* __restrict__ bias, int act,
    void* __restrict__ C, int ldc, int obf)
{
    const int tid = threadIdx.x;
    const int L = tid & 63, w = tid >> 6;
    const int m0 = blockIdx.y * 64 + (w & 1) * 32;
    const int n0 = blockIdx.x * 64 + (w >> 1) * 32;
    const int lr = L & 15;
    const int lk = (L >> 4) * 8;

    ffrag acc[2][2];
#pragma unroll
    for (int i = 0; i < 2; ++i)
#pragma unroll
        for (int j = 0; j < 2; ++j)
#pragma unroll
            for (int r = 0; r < 4; ++r) acc[i][j][r] = 0.f;

    for (int s = 0; s < 2; ++s) {
        const bf16* A = s ? A1 : A0;
        if (!A) break;
        const bf16* W = s ? W1 : W0;
        const int lda = s ? lda1 : lda0;
        const int ldw = s ? ldw1 : ldw0;
        const int K   = s ? K1 : K0;
        const bf16* a0p = A + (size_t)(m0 + lr) * lda + lk;
        const bf16* a1p = a0p + (size_t)16 * lda;
        const bf16* b0p = W + (size_t)(n0 + lr) * ldw + lk;
        const bf16* b1p = b0p + (size_t)16 * ldw;
        for (int k0 = 0; k0 < K; k0 += 32) {
            bfrag a0 = *(const bfrag*)(a0p + k0);
            bfrag a1 = *(const bfrag*)(a1p + k0);
            bfrag b0 = *(const bfrag*)(b0p + k0);
            bfrag b1 = *(const bfrag*)(b1p + k0);
            acc[0][0] = __builtin_amdgcn_mfma_f32_16x16x32_bf16(a0, b0, acc[0][0], 0, 0, 0);
            acc[0][1] = __builtin_amdgcn_mfma_f32_16x16x32_bf16(a0, b1, acc[0][1], 0, 0, 0);
            acc[1][0] = __builtin_amdgcn_mfma_f32_16x16x32_bf16(a1, b0, acc[1][0], 0, 0, 0);
            acc[1][1] = __builtin_amdgcn_mfma_f32_16x16x32_bf16(a1, b1, acc[1][1], 0, 0, 0);
        }
    }

#pragma unroll
    for (int i = 0; i < 2; ++i)
#pragma unroll
    for (int j = 0; j < 2; ++j)
#pragma unroll
    for (int r = 0; r < 4; ++r) {
        const int row = m0 + 16 * i + (L >> 4) * 4 + r;
        const int col = n0 + 16 * j + lr;
        float v = acc[i][j][r];
        if (bias) v += bias[col];
        if (act == 1) v = fmaxf(v, 0.f);
        else if (act == 2) { if (col >= 32) v = softplus_f(v); }
        else if (act == 3) { if (col < 64) v = fmaxf(v, 0.f); }
        const size_t g = (size_t)row * ldc + col;
        if (obf) ((bf16*)C)[g] = __float2bfloat16(v);
        else     ((float*)C)[g] = v;
    }
}

// ---------------------------------------------------------------------------
// encheads: per step. grid 8 WGs x 256 thr, WG handles 64 batch rows.
// Stage1: MS = ench @ MSW^T + MSB (N=64; softplus cols 32..63) -> LDS + EMSC.
// Stage2: z[64,32] = eps*std + mean (x10 on cols 0..3) -> bf16 LDS.
// Stage3: phi_z = relu(z @ pzW^T + pzb) (K=32, one MFMA per tile) -> PHIZC.
// ---------------------------------------------------------------------------
__global__ __launch_bounds__(256) void encheads_kernel(
    const bf16* __restrict__ ench,     // [512,512]
    const bf16* __restrict__ msw,      // [64,512]
    const float* __restrict__ msb,     // [64]
    const float* __restrict__ eps_t,   // [512,32] f32
    const bf16* __restrict__ pzw,      // [512,32]
    const float* __restrict__ pzb,     // [512]
    float* __restrict__ emsc_t,        // [512,64]
    bf16* __restrict__ phiz_t)         // [512,512]
{
    __shared__ float msLDS[64][64];
    __shared__ bf16 zLDS[64][32];
    const int tid = threadIdx.x;
    const int L = tid & 63, w = tid >> 6;
    const int m0 = blockIdx.x * 64;
    const int lr = L & 15;
    const int lk = (L >> 4) * 8;

    // stage 1: wave w computes rows [16w,16w+16) x all 64 cols
    ffrag acc[4];
#pragma unroll
    for (int nt = 0; nt < 4; ++nt)
#pragma unroll
        for (int r = 0; r < 4; ++r) acc[nt][r] = 0.f;

    const bf16* ap = ench + (size_t)(m0 + 16 * w + lr) * 512 + lk;
    const bf16* bp = msw + (size_t)lr * 512 + lk;
    for (int k0 = 0; k0 < 512; k0 += 32) {
        bfrag a = *(const bfrag*)(ap + k0);
#pragma unroll
        for (int nt = 0; nt < 4; ++nt) {
            bfrag b = *(const bfrag*)(bp + (size_t)(16 * nt) * 512 + k0);
            acc[nt] = __builtin_amdgcn_mfma_f32_16x16x32_bf16(a, b, acc[nt], 0, 0, 0);
        }
    }
#pragma unroll
    for (int nt = 0; nt < 4; ++nt)
#pragma unroll
    for (int r = 0; r < 4; ++r) {
        const int rl = 16 * w + (L >> 4) * 4 + r;
        const int col = 16 * nt + lr;
        float v = acc[nt][r] + msb[col];
        if (col >= 32) v = softplus_f(v);
        msLDS[rl][col] = v;
        emsc_t[(size_t)(m0 + rl) * 64 + col] = v;
    }
    __syncthreads();

    // stage 2: z
    {
        const int idx = tid * 8;
        const int row = idx >> 5, c0 = idx & 31;
#pragma unroll
        for (int j = 0; j < 8; ++j) {
            const int c = c0 + j;
            float zv = eps_t[(size_t)(m0 + row) * 32 + c] * msLDS[row][32 + c] + msLDS[row][c];
            if (c < 4) zv *= 10.f;
            zLDS[row][c] = __float2bfloat16(zv);
        }
    }
    __syncthreads();

    // stage 3: wave w covers output cols [128w, 128w+128)
    for (int nt = 0; nt < 8; ++nt) {
        const int col0 = 128 * w + 16 * nt;
        bfrag b = *(const bfrag*)(pzw + (size_t)(col0 + lr) * 32 + lk);
#pragma unroll
        for (int ms = 0; ms < 4; ++ms) {
            bfrag a = *(const bfrag*)(&zLDS[16 * ms + lr][lk]);
            ffrag c;
#pragma unroll
            for (int r = 0; r < 4; ++r) c[r] = 0.f;
            c = __builtin_amdgcn_mfma_f32_16x16x32_bf16(a, b, c, 0, 0, 0);
#pragma unroll
            for (int r = 0; r < 4; ++r) {
                const int rl = 16 * ms + (L >> 4) * 4 + r;
                const int col = col0 + lr;
                float v = fmaxf(c[r] + pzb[col], 0.f);
                phiz_t[(size_t)(m0 + rl) * 512 + col] = __float2bfloat16(v);
            }
        }
    }
}

// ---------------------------------------------------------------------------
// gru: gx = [phi_x,phi_z] @ Wih^T (separate acc) , gh = h @ Whh^T, then gates.
// grid (32 j-tiles, 8 m-blocks) x 256 thr; wave w = rows [mb*64+16w, +16),
// j-tile 16 cols. Gate g uses weight rows j+512g. Epilogue writes HLIVE f32
// and bf16 history slot.
// ---------------------------------------------------------------------------
__global__ __launch_bounds__(256) void gru_kernel(
    const bf16* __restrict__ phix_t, const bf16* __restrict__ phiz_t,
    const bf16* __restrict__ h_t,
    const bf16* __restrict__ wih,    // [1536,1024]
    const bf16* __restrict__ whh,    // [1536,512]
    float* __restrict__ hlive, bf16* __restrict__ h_next)
{
    const int tid = threadIdx.x;
    const int L = tid & 63, w = tid >> 6;
    const int j0 = blockIdx.x * 16;
    const int m0 = blockIdx.y * 64 + 16 * w;
    const int lr = L & 15;
    const int lk = (L >> 4) * 8;

    ffrag ax[3], ah[3];
#pragma unroll
    for (int g = 0; g < 3; ++g)
#pragma unroll
        for (int r = 0; r < 4; ++r) { ax[g][r] = 0.f; ah[g][r] = 0.f; }

    const size_t arow = (size_t)(m0 + lr) * 512 + lk;
    const bf16* px = phix_t + arow;
    const bf16* pz = phiz_t + arow;
    const bf16* ph = h_t + arow;
    for (int k0 = 0; k0 < 512; k0 += 32) {
        bfrag aX = *(const bfrag*)(px + k0);
        bfrag aZ = *(const bfrag*)(pz + k0);
        bfrag aH = *(const bfrag*)(ph + k0);
#pragma unroll
        for (int g = 0; g < 3; ++g) {
            const size_t wr = (size_t)(j0 + lr + 512 * g);
            bfrag bX = *(const bfrag*)(wih + wr * 1024 + lk + k0);
            bfrag bZ = *(const bfrag*)(wih + wr * 1024 + 512 + lk + k0);
            bfrag bH = *(const bfrag*)(whh + wr * 512 + lk + k0);
            ax[g] = __builtin_amdgcn_mfma_f32_16x16x32_bf16(aX, bX, ax[g], 0, 0, 0);
            ax[g] = __builtin_amdgcn_mfma_f32_16x16x32_bf16(aZ, bZ, ax[g], 0, 0, 0);
            ah[g] = __builtin_amdgcn_mfma_f32_16x16x32_bf16(aH, bH, ah[g], 0, 0, 0);
        }
    }

#pragma unroll
    for (int r = 0; r < 4; ++r) {
        const int row = m0 + (L >> 4) * 4 + r;
        const int col = j0 + lr;
        const size_t idx = (size_t)row * 512 + col;
        const float rg = sigmoid_f(ax[0][r] + ah[0][r]);
        const float zg = sigmoid_f(ax[1][r] + ah[1][r]);
        const float n  = tanhf(ax[2][r] + rg * ah[2][r]);
        const float hv = hlive[idx];
        const float hnew = (1.f - zg) * n + zg * hv;
        hlive[idx] = hnew;
        h_next[idx] = __float2bfloat16(hnew);
    }
}

// ---------------------------------------------------------------------------
// KLD: emsc [M,64] = (enc_mean | enc_std(softplused)), pms same for prior.
// ---------------------------------------------------------------------------
__global__ __launch_bounds__(256) void kld_kernel(
    const float* __restrict__ emsc, const float* __restrict__ pms,
    float* __restrict__ out)
{
    const size_t p0 = (size_t)blockIdx.x * 1024 + threadIdx.x;
    float acc = 0.f;
#pragma unroll
    for (int rep = 0; rep < 4; ++rep) {
        const size_t p = p0 + (size_t)rep * 256;
        const size_t i = p >> 5; const int c = p & 31;
        const float m1 = emsc[i * 64 + c];
        const float s1 = fmaxf(emsc[i * 64 + 32 + c], 1e-9f);
        const float m2 = pms[i * 64 + c];
        const float s2 = fmaxf(pms[i * 64 + 32 + c], 1e-9f);
        const float dm = m1 - m2;
        acc += 2.f * (logf(s2) - logf(s1)) + (s1 * s1 + dm * dm) / (s2 * s2) - 1.f;
    }
    for (int off = 32; off > 0; off >>= 1) acc += __shfl_down(acc, off);
    __shared__ float tmp[4];
    if ((threadIdx.x & 63) == 0) tmp[threadIdx.x >> 6] = acc;
    __syncthreads();
    if (threadIdx.x == 0)
        atomicAdd(out + 1, 0.5f * (tmp[0] + tmp[1] + tmp[2] + tmp[3]));
}

// ---------------------------------------------------------------------------
// final: ddc [rows,128] = (relu(dec_mean1) | dec_std_raw). dec_mean2 GEMM
// (64x64, fp32 VALU) + dec_means write + rec/nll reductions. 32 rows/block.
// ---------------------------------------------------------------------------
__global__ __launch_bounds__(256) void final_kernel(
    const float* __restrict__ ddc,
    const float* __restrict__ W2,       // dmW2 fp32 (64,64)
    const float* __restrict__ b2,
    const float* __restrict__ x,        // [rows,64]
    float* __restrict__ sums,           // [0]=rec, [2]=nll
    float* __restrict__ outDM)
{
    __shared__ float Dh[32][64];
    __shared__ float W2s[64][65];
    const int tid = threadIdx.x;
    const size_t r0 = (size_t)blockIdx.x * 32;

    for (int i = tid; i < 32 * 64; i += 256)
        Dh[i >> 6][i & 63] = ddc[(r0 + (i >> 6)) * 128 + (i & 63)];
    for (int i = tid; i < 64 * 64; i += 256) W2s[i >> 6][i & 63] = W2[i];
    __syncthreads();

    float rec = 0.f, nll = 0.f;
#pragma unroll
    for (int rep = 0; rep < 8; ++rep) {
        const int idx = rep * 256 + tid;
        const int r = idx >> 6, j = idx & 63;
        float acc = b2[j];
#pragma unroll 8
        for (int k = 0; k < 64; ++k) acc += Dh[r][k] * W2s[j][k];
        const size_t g = (r0 + r) * 64 + j;
        const float xv = x[g];
        const float sd = softplus_f(ddc[(r0 + r) * 128 + 64 + j]);
        outDM[g] = acc;
        const float d = xv - acc;
        rec += d * d;
        nll += logf(sd + 1e-5f) + 0.9189385332046727f + d * d / (2.f * sd * sd);
    }
    for (int off = 32; off > 0; off >>= 1) {
        rec += __shfl_down(rec, off);
        nll += __shfl_down(nll, off);
    }
    __shared__ float rr[4], nn[4];
    if ((tid & 63) == 0) { rr[tid >> 6] = rec; nn[tid >> 6] = nll; }
    __syncthreads();
    if (tid == 0) {
        atomicAdd(sums + 0, rr[0] + rr[1] + rr[2] + rr[3]);
        atomicAdd(sums + 2, nn[0] + nn[1] + nn[2] + nn[3]);
    }
}

// ---------------------------------------------------------------------------

static void gemm(hipStream_t s, int M, int N,
                 const bf16* A0, int lda0, const bf16* W0, int ldw0, int K0,
                 const bf16* A1, int lda1, const bf16* W1, int ldw1, int K1,
                 const float* bias, int act, void* C, int ldc, int obf)
{
    dim3 g(N / 64, M / 64), b(256);
    hipLaunchKernelGGL(mfma_gemm, g, b, 0, s,
                       A0, lda0, W0, ldw0, K0, A1, lda1, W1, ldw1, K1,
                       bias, act, C, ldc, obf);
}

static void f2b(hipStream_t s, const float* src, bf16* dst, int n) {
    hipLaunchKernelGGL(f2b_kernel, dim3((n + 255) / 256), dim3(256), 0, s, src, dst, n);
}
static void fcp(hipStream_t s, const float* src, float* dst, int n) {
    hipLaunchKernelGGL(fcopy_kernel, dim3((n + 255) / 256), dim3(256), 0, s, src, dst, n);
}

// bf16-weight element offsets within WB
#define O_PXW1 0
#define O_PXW2 32768
#define O_PZW  294912
#define O_EW1  311296
#define O_EW2  835584
#define O_MSW  1097728
#define O_PRW  1130496
#define O_PMSW 1392640
#define O_DW1  1425408
#define O_DW2  1949696
#define O_DDW  2211840
#define O_GWIH 2277376
#define O_GWHH 3850240
#define WB_ELEMS 4636672ull

static size_t ws_needed(int tc) {
    return 28673024ull + (size_t)tc * 2490368ull;
}

extern "C" void kernel_launch(void* const* d_in, const int* in_sizes, int n_in,
                              void* d_out, int out_size, void* d_ws, size_t ws_size,
                              hipStream_t stream)
{
    const float* x_in   = (const float*)d_in[0];
    const float* eps_in = (const float*)d_in[1];
    const float* pxW1 = (const float*)d_in[2];  const float* pxb1 = (const float*)d_in[3];
    const float* pxW2 = (const float*)d_in[4];  const float* pxb2 = (const float*)d_in[5];
    const float* pzW  = (const float*)d_in[6];  const float* pzb  = (const float*)d_in[7];
    const float* eW1  = (const float*)d_in[8];  const float* eb1  = (const float*)d_in[9];
    const float* eW2  = (const float*)d_in[10]; const float* eb2  = (const float*)d_in[11];
    const float* emW  = (const float*)d_in[12]; const float* emb  = (const float*)d_in[13];
    const float* esW  = (const float*)d_in[14]; const float* esb  = (const float*)d_in[15];
    const float* prW  = (const float*)d_in[16]; const float* prb  = (const float*)d_in[17];
    const float* pmW  = (const float*)d_in[18]; const float* pmb  = (const float*)d_in[19];
    const float* psW  = (const float*)d_in[20]; const float* psb  = (const float*)d_in[21];
    const float* dW1  = (const float*)d_in[22]; const float* db1  = (const float*)d_in[23];
    const float* dW2  = (const float*)d_in[24]; const float* db2  = (const float*)d_in[25];
    const float* dsW  = (const float*)d_in[26]; const float* dsb  = (const float*)d_in[27];
    const float* dmW1 = (const float*)d_in[28]; const float* dmb1 = (const float*)d_in[29];
    const float* dmW2 = (const float*)d_in[30]; const float* dmb2 = (const float*)d_in[31];
    const float* gWih = (const float*)d_in[32]; const float* gWhh = (const float*)d_in[33];

    float* out = (float*)d_out;
    char* ws = (char*)d_ws;

    int TC = 1;
    const int cands[9] = {256, 128, 64, 32, 16, 8, 4, 2, 1};
    for (int i = 0; i < 9; ++i)
        if (ws_needed(cands[i]) <= ws_size) { TC = cands[i]; break; }
    const int NCH = 256 / TC;

    // ---- workspace map (all offsets 512B-aligned) ----
    bf16*  WB    = (bf16*)(ws);                         // 9,273,344 B
    float* BB    = (float*)(ws + 9273344ull);           // 1024 B combined biases
    bf16*  XBF   = (bf16*)(ws + 9274368ull);            // 16,777,216 B
    float* HLIVE = (float*)(ws + 26051584ull);          // 1,048,576 B
    bf16*  EH1   = (bf16*)(ws + 27100160ull);           // 524,288 B
    bf16*  ENCH  = (bf16*)(ws + 27624448ull);           // 524,288 B
    bf16*  HH    = (bf16*)(ws + 28148736ull);           // (TC+1)*524,288 B
    size_t off = 28148736ull + (size_t)(TC + 1) * 524288ull;
    bf16*  R1    = (bf16*)(ws + off); off += (size_t)TC * 524288ull;
    bf16*  R2    = (bf16*)(ws + off); off += (size_t)TC * 524288ull;   // PHIX / DECH
    bf16*  PHIZC = (bf16*)(ws + off); off += (size_t)TC * 524288ull;
    float* EMSC  = (float*)(ws + off); off += (size_t)TC * 131072ull;
    float* U     = (float*)(ws + off);                  // TC*262,144 B (PMS then DDC)

    // ---- setup: weight/bias/x conversion ----
    f2b(stream, pxW1, WB + O_PXW1, 32768);
    f2b(stream, pxW2, WB + O_PXW2, 262144);
    f2b(stream, pzW,  WB + O_PZW,  16384);
    f2b(stream, eW1,  WB + O_EW1,  524288);
    f2b(stream, eW2,  WB + O_EW2,  262144);
    f2b(stream, emW,  WB + O_MSW,  16384);
    f2b(stream, esW,  WB + O_MSW + 16384, 16384);
    f2b(stream, prW,  WB + O_PRW,  262144);
    f2b(stream, pmW,  WB + O_PMSW, 16384);
    f2b(stream, psW,  WB + O_PMSW + 16384, 16384);
    f2b(stream, dW1,  WB + O_DW1,  524288);
    f2b(stream, dW2,  WB + O_DW2,  262144);
    f2b(stream, dmW1, WB + O_DDW,  32768);
    f2b(stream, dsW,  WB + O_DDW + 32768, 32768);
    f2b(stream, gWih, WB + O_GWIH, 1572864);
    f2b(stream, gWhh, WB + O_GWHH, 786432);
    f2b(stream, x_in, XBF, 8388608);
    fcp(stream, emb,  BB + 0,   32);
    fcp(stream, esb,  BB + 32,  32);
    fcp(stream, pmb,  BB + 64,  32);
    fcp(stream, psb,  BB + 96,  32);
    fcp(stream, dmb1, BB + 128, 64);
    fcp(stream, dsb,  BB + 192, 64);

    hipLaunchKernelGGL(init_kernel, dim3(1024), dim3(256), 0, stream, HLIVE, HH, out);

    for (int c = 0; c < NCH; ++c) {
        const int cs = c * TC;
        const int MR = TC * 512;

        if (c > 0)
            hipLaunchKernelGGL(snap_kernel, dim3(1024), dim3(256), 0, stream,
                               HH + (size_t)TC * 262144, HH);

        // ---- pre: phi_x MLP for the chunk ----
        gemm(stream, MR, 512, XBF + (size_t)cs * 32768, 64, WB + O_PXW1, 64, 64,
             nullptr, 0, nullptr, 0, 0, pxb1, 1, R1, 512, 1);
        gemm(stream, MR, 512, R1, 512, WB + O_PXW2, 512, 512,
             nullptr, 0, nullptr, 0, 0, pxb2, 1, R2, 512, 1);

        // ---- sequential steps (4 launches each) ----
        for (int lt = 0; lt < TC; ++lt) {
            const int t = cs + lt;
            const bf16* phix_t = R2 + (size_t)lt * 262144;
            const bf16* h_t    = HH + (size_t)lt * 262144;
            gemm(stream, 512, 512, phix_t, 512, WB + O_EW1, 1024, 512,
                 h_t, 512, WB + O_EW1 + 512, 1024, 512, eb1, 1, EH1, 512, 1);
            gemm(stream, 512, 512, EH1, 512, WB + O_EW2, 512, 512,
                 nullptr, 0, nullptr, 0, 0, eb2, 1, ENCH, 512, 1);
            hipLaunchKernelGGL(encheads_kernel, dim3(8), dim3(256), 0, stream,
                               ENCH, WB + O_MSW, BB,
                               eps_in + (size_t)t * 16384, WB + O_PZW, pzb,
                               EMSC + (size_t)lt * 32768, PHIZC + (size_t)lt * 262144);
            hipLaunchKernelGGL(gru_kernel, dim3(32, 8), dim3(256), 0, stream,
                               phix_t, PHIZC + (size_t)lt * 262144, h_t,
                               WB + O_GWIH, WB + O_GWHH,
                               HLIVE, HH + (size_t)(lt + 1) * 262144);
        }

        // ---- post: prior + KLD ----
        gemm(stream, MR, 512, HH, 512, WB + O_PRW, 512, 512,
             nullptr, 0, nullptr, 0, 0, prb, 1, R1, 512, 1);
        gemm(stream, MR, 64, R1, 512, WB + O_PMSW, 512, 512,
             nullptr, 0, nullptr, 0, 0, BB + 64, 2, U, 64, 0);
        hipLaunchKernelGGL(kld_kernel, dim3(TC * 16), dim3(256), 0, stream,
                           EMSC, U, out);

        // ---- post: dec + NLL/rec ----
        gemm(stream, MR, 512, PHIZC, 512, WB + O_DW1, 1024, 512,
             HH, 512, WB + O_DW1 + 512, 1024, 512, db1, 1, R1, 512, 1);
        gemm(stream, MR, 512, R1, 512, WB + O_DW2, 512, 512,
             nullptr, 0, nullptr, 0, 0, db2, 1, R2, 512, 1);          // R2: PHIX dead
        gemm(stream, MR, 128, R2, 512, WB + O_DDW, 512, 512,
             nullptr, 0, nullptr, 0, 0, BB + 128, 3, U, 128, 0);
        hipLaunchKernelGGL(final_kernel, dim3(MR / 32), dim3(256), 0, stream,
                           U, dmW2, dmb2, x_in + (size_t)cs * 32768,
                           out, out + 3 + (size_t)cs * 32768);
    }
}